// Round 7
// baseline (1093.414 us; speedup 1.0000x reference)
//
#include <hip/hip_runtime.h>

// ---------------------------------------------------------------------------
// ContrastiveLoss: loss = mean_i [ 0.5*(LSE_row_i + LSE_col_i) - diag_i ]
// over logits = normalize(img) @ normalize(txt)^T / 0.07, N=8192, D=1024.
// |logit| <= 14.29 -> exp() safe in fp32, no max subtraction needed.
//
// R21 = R15's PROVEN geometry (256x256, 8 waves 2x4 of 128x64, dbuf 128KB,
// VGPR 128 no-spill) + single-barrier schedule. R17-R20's 4-wave/128x128
// geometry spilled unfixably (acc=256 regs; R20: 145MB scratch traffic).
// R15's stall was structural: TWO barriers bracketing the read->MFMA dep
// serialize read-issue + latency + MFMA (7553 cy/tile vs ~2400 ideal).
// Single-barrier dbuf schedule, per tile t:
//   vmcnt(0)        // stage(t) issued a full tile ago -> ~free
//   s_barrier       // all waves passed lgkm-drain of reads(t-1)
//   stage(t+1) -> buf^1   // overwrites tile t-1's data: WAR-safe
//   bg[0..3], af0, af1 <- buf[t&1]    // critical-path reads first
//   4 phases: {rolling af-pair prefetch; 8 MFMA}  // compiler fine-lgkm
//   (trailing lgkmcnt(0) folds into last MFMA's operand wait)
// NO barrier between reads and MFMAs -> compiler interleaves them
// (m97 asm: fine lgkmcnt(4/3/1/0)); first MFMA starts ~190cy into the
// tile instead of after full read-drain. setprio(1) wraps the MFMA run
// (single-barrier structure lets waves drift into reader/MFMA roles --
// the T5 precondition the lockstep R15/R16 lacked).
// Ceiling check: LDS pipe 2000 cy/CU/tile ~ MFMA 2176 cy -> MFMA-bound.
// vmcnt ledger: only stage(t+1)'s 8/thread outstanding at tile t+1 start
// -> vmcnt(0) retires exactly those, issued ~2500cy earlier (HBM ~900).
// Carried: R7/R10 producer chunk-interleave -> 0-conflict b128 LDS reads
// (slot = quad ^ ((row>>1)&3)); R13 inverted XCD swizzle; R4/R1 swizzle
// identities ((row>>1)&3 invariant under +128 rows).
// ---------------------------------------------------------------------------

#define BM 256
#define BN 256
#define BKB 128   // fp8 K-bytes per iteration (one MFMA k-step)

typedef float floatx4 __attribute__((ext_vector_type(4)));
typedef int   intx4   __attribute__((ext_vector_type(4)));
typedef int   intx8   __attribute__((ext_vector_type(8)));

__device__ __forceinline__ void gload_lds16(const unsigned char* g, unsigned char* lds) {
    __builtin_amdgcn_global_load_lds(
        (const __attribute__((address_space(1))) void*)g,
        (__attribute__((address_space(3))) void*)lds,
        16, 0, 0);
}

// ---- Kernel 1: row L2-normalize, x16, fp32 -> fp8 e4m3, chunk-interleaved --
__global__ __launch_bounds__(256)
void normalize_fp8(const float* __restrict__ img, const float* __restrict__ txt,
                   unsigned int* __restrict__ oimg, unsigned int* __restrict__ otxt,
                   float* __restrict__ sums, float* __restrict__ out, int N) {
    const int gi = blockIdx.x * 256 + threadIdx.x;
    if (gi < 2 * N) sums[gi] = 0.f;
    if (gi == 0) out[0] = 0.f;

    const int gw = blockIdx.x * 4 + (threadIdx.x >> 6);   // row id in [0,2N)
    const int lane = threadIdx.x & 63;
    const float* in = (gw < N) ? img : txt;
    unsigned int* o = (gw < N) ? oimg : otxt;
    const int row = (gw < N) ? gw : gw - N;
    const float4* rp = (const float4*)(in + (size_t)row * 1024);

    float4 v[4];
    float ss = 0.f;
    #pragma unroll
    for (int j = 0; j < 4; ++j) {
        v[j] = rp[j * 64 + lane];
        ss += v[j].x * v[j].x + v[j].y * v[j].y + v[j].z * v[j].z + v[j].w * v[j].w;
    }
    #pragma unroll
    for (int o2 = 1; o2 < 64; o2 <<= 1) ss += __shfl_xor(ss, o2);
    const float inv = 16.0f / fmaxf(sqrtf(ss), 1e-8f);   // x16 quantization scale
    #pragma unroll
    for (int j = 0; j < 4; ++j) {
        int p = __builtin_amdgcn_cvt_pk_fp8_f32(v[j].x * inv, v[j].y * inv, 0, false);
        p = __builtin_amdgcn_cvt_pk_fp8_f32(v[j].z * inv, v[j].w * inv, p, true);
        const int d = j * 64 + lane;
        const int c = (d >> 2) & 7;
        const int pp = (c & 1) * 4 + (c >> 1);
        const int dp = (d & ~31) | (pp * 4 + (d & 3));
        o[(size_t)row * 256 + dp] = (unsigned int)p;
    }
}

#define MF(a, b, c) __builtin_amdgcn_mfma_scale_f32_16x16x128_f8f6f4( \
        (a), (b), (c), 0, 0, 0, 127, 0, 127)

// One K-tile. CUR/NXT/DO_ST are literals; T_ wave-uniform runtime.
#define ITER(T_, CUR, NXT, DO_ST) do { \
    asm volatile("s_waitcnt vmcnt(0)" ::: "memory"); \
    __builtin_amdgcn_s_barrier(); \
    const unsigned char* Ac = As + (CUR) * 32768; \
    const unsigned char* Bc = Bs + (CUR) * 32768; \
    bg[0] = rdB(Bc, 0); bg[1] = rdB(Bc, 1); \
    bg[2] = rdB(Bc, 2); bg[3] = rdB(Bc, 3); \
    af[0][0] = rdA(Ac, 0); af[0][1] = rdA(Ac, 1); \
    if (DO_ST) { stageA(((T_) + 1) * BKB, (NXT) * 32768); \
                 stageB(((T_) + 1) * BKB, (NXT) * 32768); } \
    __builtin_amdgcn_s_setprio(1); \
    _Pragma("unroll") \
    for (int p = 0; p < 4; ++p) { \
        if (p < 3) { \
            af[(p + 1) & 1][0] = rdA(Ac, 2 * p + 2); \
            af[(p + 1) & 1][1] = rdA(Ac, 2 * p + 3); \
        } \
        _Pragma("unroll") \
        for (int u = 0; u < 2; ++u) \
            _Pragma("unroll") \
            for (int tn = 0; tn < 4; ++tn) \
                acc[2 * p + u][tn] = MF(af[p & 1][u], bg[tn], acc[2 * p + u][tn]); \
    } \
    __builtin_amdgcn_s_setprio(0); \
    asm volatile("s_waitcnt lgkmcnt(0)" ::: "memory"); \
} while (0)

// ---- Kernel 2: 256x256-tile NT MX-fp8 GEMM + fused exp/row-col sums/diag ---
__global__ __launch_bounds__(512, 2)
void gemm_exp_kernel(const unsigned char* __restrict__ A,   // img_q [N][K] fp8 (interleaved)
                     const unsigned char* __restrict__ B,   // txt_q [N][K] fp8 (interleaved)
                     float* __restrict__ rowsum, float* __restrict__ colsum,
                     float* __restrict__ diag, int K, float scale) {
    // XCD-inverted swizzle: xcd = id&7 owns bm strip [xcd*4, xcd*4+4).
    const int id = blockIdx.x;
    const int idp = id >> 3;
    const int bm = (id & 7) * 4 + (idp & 3);
    const int bn = idp >> 2;

    // LDS per matrix: [buf:32768][win:16384][row:64][slot:16];
    // slot s of row r holds global chunk s ^ ((r>>1)&3) of that window.
    __shared__ unsigned char As[2 * 2 * 256 * 64];   // 64 KB
    __shared__ unsigned char Bs[2 * 2 * 256 * 64];   // 64 KB

    const int tid = threadIdx.x;
    const int lane = tid & 63;
    const int wave = tid >> 6;           // 0..7
    const int quad = lane >> 4;
    const int lanelo = lane & 15;
    const int wrow = (wave >> 2) * 128;  // output row strip
    const int wcol = (wave & 3) * 64;    // output col strip

    floatx4 acc[8][4] = {};
    intx8 af[2][2];
    intx8 bg[4];

    // ---- staging: thread t covers chunk c = t + 512j, j=0..3, per matrix ----
    // c -> win = c>>10, row = (c>>2)&255 = r0 + (j&1)*128, slot = t&3;
    // LDS addr = c*16 = t*16 + j*8192.
    const int r0 = tid >> 2;             // 0..127
    const int xa = ((tid & 3) ^ ((r0 >> 1) & 3)) * 16;  // +128 rows: invariant
    const unsigned char* pa = A + ((size_t)bm * BM + r0) * K + xa;
    const unsigned char* pb = B + ((size_t)bn * BN + r0) * K + xa;
    unsigned char* lA = As + tid * 16;
    unsigned char* lB = Bs + tid * 16;

    auto stageA = [&](int k2, int bo) {
        #pragma unroll
        for (int j = 0; j < 4; ++j) {
            const int ro = (j & 1) * 128;
            const int wo = (j >> 1) * 64;
            gload_lds16(pa + (size_t)ro * K + wo + k2, lA + bo + j * 8192);
        }
    };
    auto stageB = [&](int k2, int bo) {
        #pragma unroll
        for (int j = 0; j < 4; ++j) {
            const int ro = (j & 1) * 128;
            const int wo = (j >> 1) * 64;
            gload_lds16(pb + (size_t)ro * K + wo + k2, lB + bo + j * 8192);
        }
    };

    // ---- fragment read offsets (zero-conflict chunk-interleave geometry) ----
    const int swx = (quad ^ ((lanelo >> 1) & 3)) * 16;
    const int aoffB = (wrow + lanelo) * 64 + swx;
    const int boffB = (wcol + lanelo) * 64 + swx;

    auto rdA = [&](const unsigned char* Ab, int tm) -> intx8 {
        const intx4 lo = *(const intx4*)(Ab + aoffB + tm * 1024);
        const intx4 hi = *(const intx4*)(Ab + 16384 + aoffB + tm * 1024);
        return __builtin_shufflevector(lo, hi, 0, 1, 2, 3, 4, 5, 6, 7);
    };
    auto rdB = [&](const unsigned char* Bb, int tn) -> intx8 {
        const intx4 lo = *(const intx4*)(Bb + boffB + tn * 1024);
        const intx4 hi = *(const intx4*)(Bb + 16384 + boffB + tn * 1024);
        return __builtin_shufflevector(lo, hi, 0, 1, 2, 3, 4, 5, 6, 7);
    };

    // ---- prologue: stage tile 0 only (8 gloads/thread) ----
    stageA(0, 0);
    stageB(0, 0);

    // ---- 8 K-tiles: t=0..5 rolled (3 x unroll-2), t=6,7 peeled ----
    for (int tt = 0; tt < 3; ++tt) {
        ITER(2 * tt,     0, 1, 1);
        ITER(2 * tt + 1, 1, 0, 1);
    }
    ITER(6, 0, 1, 1);
    ITER(7, 1, 0, 0);

    // ---- epilogue: scale, capture diag, exp in place ----
    const int growb = bm * BM + wrow;
    const int gcolb = bn * BN + wcol;

    #pragma unroll
    for (int tm = 0; tm < 8; ++tm)
        #pragma unroll
        for (int tn = 0; tn < 4; ++tn)
            #pragma unroll
            for (int r = 0; r < 4; ++r) {
                const float l = acc[tm][tn][r] * scale;
                const int grow = growb + tm * 16 + quad * 4 + r;
                const int gcol = gcolb + tn * 16 + lanelo;
                if (grow == gcol) diag[grow] = l;
                acc[tm][tn][r] = __expf(l);
            }

    // ---- row sums: reduce over the 16 lanes sharing a row, then atomicAdd ----
    #pragma unroll
    for (int tm = 0; tm < 8; ++tm) {
        floatx4 rs = acc[tm][0] + acc[tm][1] + acc[tm][2] + acc[tm][3];
        #pragma unroll
        for (int r = 0; r < 4; ++r) {
            float v = rs[r];
            v += __shfl_xor(v, 1);
            v += __shfl_xor(v, 2);
            v += __shfl_xor(v, 4);
            v += __shfl_xor(v, 8);
            if (lanelo == 0)
                atomicAdd(&rowsum[growb + tm * 16 + quad * 4 + r], v);
        }
    }

    // ---- col sums: reduce over quads (xor 16, 32), then atomicAdd ----
    #pragma unroll
    for (int tn = 0; tn < 4; ++tn) {
        float cs = 0.f;
        #pragma unroll
        for (int tm = 0; tm < 8; ++tm)
            cs += acc[tm][tn][0] + acc[tm][tn][1] + acc[tm][tn][2] + acc[tm][tn][3];
        cs += __shfl_xor(cs, 16);
        cs += __shfl_xor(cs, 32);
        if (quad == 0)
            atomicAdd(&colsum[gcolb + tn * 16 + lanelo], cs);
    }
}

// ---- Kernel 3: loss = mean( 0.5*(log(rowsum)+log(colsum)) - diag ) ---------
__global__ __launch_bounds__(256)
void final_reduce(const float* __restrict__ rowsum, const float* __restrict__ colsum,
                  const float* __restrict__ diag, float* __restrict__ out, int n) {
    const int i = blockIdx.x * 256 + threadIdx.x;
    const int t = threadIdx.x;
    float v = 0.5f * (logf(rowsum[i]) + logf(colsum[i])) - diag[i];
    #pragma unroll
    for (int o = 1; o < 64; o <<= 1) v += __shfl_xor(v, o);
    __shared__ float ws[4];
    if ((t & 63) == 0) ws[t >> 6] = v;
    __syncthreads();
    if (t == 0) atomicAdd(out, (ws[0] + ws[1] + ws[2] + ws[3]) / (float)n);
}

extern "C" void kernel_launch(void* const* d_in, const int* in_sizes, int n_in,
                              void* d_out, int out_size, void* d_ws, size_t ws_size,
                              hipStream_t stream) {
    const float* img = (const float*)d_in[0];
    const float* txt = (const float*)d_in[1];
    float* out = (float*)d_out;

    const int D = 1024;
    const int N = in_sizes[0] / D;   // 8192

    unsigned char* imgq = (unsigned char*)d_ws;
    unsigned char* txtq = imgq + (size_t)N * D;
    float* rowsum = (float*)(txtq + (size_t)N * D);   // rowsum[N] ++ colsum[N]
    float* colsum = rowsum + N;
    float* diag = colsum + N;

    normalize_fp8<<<2 * N / 4, 256, 0, stream>>>(img, txt, (unsigned int*)imgq,
                                                 (unsigned int*)txtq, rowsum, out, N);

    // acc = sum of (16a)(16b) = 256*cos; scale undoes 256 and applies 1/T.
    gemm_exp_kernel<<<(N / BM) * (N / BN), 512, 0, stream>>>(
        imgq, txtq, rowsum, colsum, diag, D, 1.0f / (256.0f * 0.07f));
    final_reduce<<<N / 256, 256, 0, stream>>>(rowsum, colsum, diag, out, N);
}

// Round 8
// 953.957 us; speedup vs baseline: 1.1462x; 1.1462x over previous
//
#include <hip/hip_runtime.h>

// ---------------------------------------------------------------------------
// ContrastiveLoss: loss = mean_i [ 0.5*(LSE_row_i + LSE_col_i) - diag_i ]
// over logits = normalize(img) @ normalize(txt)^T / 0.07, N=8192, D=1024.
// |logit| <= 14.29 -> exp() safe in fp32, no max subtraction needed.
//
// R22 = small-acc pipelined GEMM. Spill ledger: R19/R20 (acc=256) and R21
// (acc=128 + rolling pipeline) all spilled (GB-scale FETCH/WRITE scratch
// traffic); R15 (acc=128, serialized) fit but ran 100.7us. Resolution:
// shrink acc to 64 (BM=128 x BN=256, 8 waves of 64x64 each) so the
// register-level pipeline fits: at launch_bounds(512,2) cap=256/wave,
// acc 64 + bg[4]=32 + af[2] rolling=16 + inflight/ptrs ~110 => ~190 used.
// LDS 96KB (A 32KB + B 64KB, dbuf, 1 block/CU, 2 waves/SIMD).
// Single-barrier dbuf schedule per tile t:
//   vmcnt(0)   // stage(t), issued one full tile ago (~1375cy cover) -> ~free
//   s_barrier  // all waves' reads(t-1) drained (trailing lgkmcnt(0))
//   bg[0..3] <- Bs[cur]; af[0] <- As[cur]      // critical-path reads
//   stage(t+1) -> buf^1                        // WAR-safe overwrite of t-1
//   setprio(1); 4 phases { af[(p+1)&1] prefetch; 4 MFMA }; setprio(0)
//   lgkmcnt(0)  // own reads complete before next barrier
// NO barrier between reads and MFMAs -> compiler's fine lgkmcnt interleave.
// Cycle model: LDS/CU/tile = 128KB reads + 48KB stage = 1375cy; MFMA/SIMD
// = 32x34.5 = 1104cy -> ~1375cy/tile, 8 tiles + prologue => ~45-55us gemm
// (vs 100.7 serialized). LDS-bound floor 37.6us; MFMA floor 29.5us.
// Carried: R7/R10 producer chunk-interleave -> 0-conflict b128 LDS reads
// (slot = quad ^ ((row>>1)&3)); bijective XCD swizzle (2048 = 8 x 256);
// R4/R1 swizzle identities ((row>>1)&3 invariant under +64/+128 rows).
// ---------------------------------------------------------------------------

#define BM 128
#define BN 256
#define BKB 128   // fp8 K-bytes per iteration (one MFMA k-step)

typedef float floatx4 __attribute__((ext_vector_type(4)));
typedef int   intx4   __attribute__((ext_vector_type(4)));
typedef int   intx8   __attribute__((ext_vector_type(8)));

__device__ __forceinline__ void gload_lds16(const unsigned char* g, unsigned char* lds) {
    __builtin_amdgcn_global_load_lds(
        (const __attribute__((address_space(1))) void*)g,
        (__attribute__((address_space(3))) void*)lds,
        16, 0, 0);
}

// ---- Kernel 1: row L2-normalize, x16, fp32 -> fp8 e4m3, chunk-interleaved --
__global__ __launch_bounds__(256)
void normalize_fp8(const float* __restrict__ img, const float* __restrict__ txt,
                   unsigned int* __restrict__ oimg, unsigned int* __restrict__ otxt,
                   float* __restrict__ sums, float* __restrict__ out, int N) {
    const int gi = blockIdx.x * 256 + threadIdx.x;
    if (gi < 2 * N) sums[gi] = 0.f;
    if (gi == 0) out[0] = 0.f;

    const int gw = blockIdx.x * 4 + (threadIdx.x >> 6);   // row id in [0,2N)
    const int lane = threadIdx.x & 63;
    const float* in = (gw < N) ? img : txt;
    unsigned int* o = (gw < N) ? oimg : otxt;
    const int row = (gw < N) ? gw : gw - N;
    const float4* rp = (const float4*)(in + (size_t)row * 1024);

    float4 v[4];
    float ss = 0.f;
    #pragma unroll
    for (int j = 0; j < 4; ++j) {
        v[j] = rp[j * 64 + lane];
        ss += v[j].x * v[j].x + v[j].y * v[j].y + v[j].z * v[j].z + v[j].w * v[j].w;
    }
    #pragma unroll
    for (int o2 = 1; o2 < 64; o2 <<= 1) ss += __shfl_xor(ss, o2);
    const float inv = 16.0f / fmaxf(sqrtf(ss), 1e-8f);   // x16 quantization scale
    #pragma unroll
    for (int j = 0; j < 4; ++j) {
        int p = __builtin_amdgcn_cvt_pk_fp8_f32(v[j].x * inv, v[j].y * inv, 0, false);
        p = __builtin_amdgcn_cvt_pk_fp8_f32(v[j].z * inv, v[j].w * inv, p, true);
        const int d = j * 64 + lane;
        const int c = (d >> 2) & 7;
        const int pp = (c & 1) * 4 + (c >> 1);
        const int dp = (d & ~31) | (pp * 4 + (d & 3));
        o[(size_t)row * 256 + dp] = (unsigned int)p;
    }
}

#define MF(a, b, c) __builtin_amdgcn_mfma_scale_f32_16x16x128_f8f6f4( \
        (a), (b), (c), 0, 0, 0, 127, 0, 127)

// One K-tile. CUR/NXT/DO_ST are literals; T_ wave-uniform runtime.
#define ITER(T_, CUR, NXT, DO_ST) do { \
    asm volatile("s_waitcnt vmcnt(0)" ::: "memory"); \
    __builtin_amdgcn_s_barrier(); \
    const unsigned char* Ac = As + (CUR) * 16384; \
    const unsigned char* Bc = Bs + (CUR) * 32768; \
    bg[0] = rdB(Bc, 0); bg[1] = rdB(Bc, 1); \
    bg[2] = rdB(Bc, 2); bg[3] = rdB(Bc, 3); \
    af[0] = rdA(Ac, 0); \
    if (DO_ST) { stageA(((T_) + 1) * BKB, (NXT) * 16384); \
                 stageB(((T_) + 1) * BKB, (NXT) * 32768); } \
    __builtin_amdgcn_s_setprio(1); \
    _Pragma("unroll") \
    for (int p = 0; p < 4; ++p) { \
        if (p < 3) af[(p + 1) & 1] = rdA(Ac, p + 1); \
        _Pragma("unroll") \
        for (int tn = 0; tn < 4; ++tn) \
            acc[p][tn] = MF(af[p & 1], bg[tn], acc[p][tn]); \
    } \
    __builtin_amdgcn_s_setprio(0); \
    asm volatile("s_waitcnt lgkmcnt(0)" ::: "memory"); \
} while (0)

// ---- Kernel 2: 128x256-tile NT MX-fp8 GEMM + fused exp/row-col sums/diag ---
__global__ __launch_bounds__(512, 2)
void gemm_exp_kernel(const unsigned char* __restrict__ A,   // img_q [N][K] fp8 (interleaved)
                     const unsigned char* __restrict__ B,   // txt_q [N][K] fp8 (interleaved)
                     float* __restrict__ rowsum, float* __restrict__ colsum,
                     float* __restrict__ diag, int K, float scale) {
    // Bijective XCD swizzle for 2048 = 8 xcd x 256: xcd owns bm strip
    // [xcd*8, xcd*8+8) x all bn; within xcd, bm inner (8) then bn (32).
    const int id = blockIdx.x;
    const int pos = id >> 3;
    const int bm = (id & 7) * 8 + (pos & 7);   // 0..63
    const int bn = pos >> 3;                   // 0..31

    // LDS: A [buf:16384][win:8192][row128:64][slot:16] = 32 KB;
    //      B [buf:32768][win:16384][row256:64][slot:16] = 64 KB.
    // slot s of row r holds global chunk s ^ ((r>>1)&3) of that window.
    __shared__ unsigned char As[2 * 2 * 128 * 64];   // 32 KB
    __shared__ unsigned char Bs[2 * 2 * 256 * 64];   // 64 KB

    const int tid = threadIdx.x;
    const int lane = tid & 63;
    const int wave = tid >> 6;           // 0..7
    const int quad = lane >> 4;
    const int lanelo = lane & 15;
    const int wrow = (wave >> 2) * 64;   // output row strip (2 of 64)
    const int wcol = (wave & 3) * 64;    // output col strip (4 of 64)

    floatx4 acc[4][4] = {};
    intx8 af[2];
    intx8 bg[4];

    // ---- staging addresses (512 threads; A: 2 chunks/thr, B: 4 chunks/thr) --
    const int r0 = tid >> 2;             // 0..127
    const int xa = ((tid & 3) ^ ((r0 >> 1) & 3)) * 16;  // +128 rows: invariant
    const unsigned char* pa = A + ((size_t)bm * BM + r0) * K + xa;
    const unsigned char* pb = B + ((size_t)bn * BN + r0) * K + xa;
    unsigned char* lA = As + tid * 16;
    unsigned char* lB = Bs + tid * 16;

    auto stageA = [&](int k2, int bo) {   // rows 0..127, windows 0,1
        gload_lds16(pa + k2,      lA + bo);
        gload_lds16(pa + k2 + 64, lA + bo + 8192);
    };
    auto stageB = [&](int k2, int bo) {   // rows 0..255, windows 0,1
        #pragma unroll
        for (int j = 0; j < 4; ++j) {
            const int ro = (j & 1) * 128;
            const int wo = (j >> 1) * 64;
            gload_lds16(pb + (size_t)ro * K + wo + k2, lB + bo + j * 8192);
        }
    };

    // ---- fragment read offsets (zero-conflict chunk-interleave geometry) ----
    const int swx = (quad ^ ((lanelo >> 1) & 3)) * 16;
    const int aoffB = (wrow + lanelo) * 64 + swx;
    const int boffB = (wcol + lanelo) * 64 + swx;

    auto rdA = [&](const unsigned char* Ab, int tm) -> intx8 {
        const intx4 lo = *(const intx4*)(Ab + aoffB + tm * 1024);
        const intx4 hi = *(const intx4*)(Ab + 8192 + aoffB + tm * 1024);
        return __builtin_shufflevector(lo, hi, 0, 1, 2, 3, 4, 5, 6, 7);
    };
    auto rdB = [&](const unsigned char* Bb, int tn) -> intx8 {
        const intx4 lo = *(const intx4*)(Bb + boffB + tn * 1024);
        const intx4 hi = *(const intx4*)(Bb + 16384 + boffB + tn * 1024);
        return __builtin_shufflevector(lo, hi, 0, 1, 2, 3, 4, 5, 6, 7);
    };

    // ---- prologue: stage tile 0 (6 gloads/thread) ----
    stageA(0, 0);
    stageB(0, 0);

    // ---- 8 K-tiles: t=0..5 rolled (3 x unroll-2), t=6,7 peeled ----
    for (int tt = 0; tt < 3; ++tt) {
        ITER(2 * tt,     0, 1, 1);
        ITER(2 * tt + 1, 1, 0, 1);
    }
    ITER(6, 0, 1, 1);
    ITER(7, 1, 0, 0);

    // ---- epilogue: scale, capture diag, exp in place ----
    const int growb = bm * BM + wrow;
    const int gcolb = bn * BN + wcol;

    #pragma unroll
    for (int tm = 0; tm < 4; ++tm)
        #pragma unroll
        for (int tn = 0; tn < 4; ++tn)
            #pragma unroll
            for (int r = 0; r < 4; ++r) {
                const float l = acc[tm][tn][r] * scale;
                const int grow = growb + tm * 16 + quad * 4 + r;
                const int gcol = gcolb + tn * 16 + lanelo;
                if (grow == gcol) diag[grow] = l;
                acc[tm][tn][r] = __expf(l);
            }

    // ---- row sums: reduce over the 16 lanes sharing a row, then atomicAdd ----
    #pragma unroll
    for (int tm = 0; tm < 4; ++tm) {
        floatx4 rs = acc[tm][0] + acc[tm][1] + acc[tm][2] + acc[tm][3];
        #pragma unroll
        for (int r = 0; r < 4; ++r) {
            float v = rs[r];
            v += __shfl_xor(v, 1);
            v += __shfl_xor(v, 2);
            v += __shfl_xor(v, 4);
            v += __shfl_xor(v, 8);
            if (lanelo == 0)
                atomicAdd(&rowsum[growb + tm * 16 + quad * 4 + r], v);
        }
    }

    // ---- col sums: reduce over quads (xor 16, 32), then atomicAdd ----
    #pragma unroll
    for (int tn = 0; tn < 4; ++tn) {
        float cs = 0.f;
        #pragma unroll
        for (int tm = 0; tm < 4; ++tm)
            cs += acc[tm][tn][0] + acc[tm][tn][1] + acc[tm][tn][2] + acc[tm][tn][3];
        cs += __shfl_xor(cs, 16);
        cs += __shfl_xor(cs, 32);
        if (quad == 0)
            atomicAdd(&colsum[gcolb + tn * 16 + lanelo], cs);
    }
}

// ---- Kernel 3: loss = mean( 0.5*(log(rowsum)+log(colsum)) - diag ) ---------
__global__ __launch_bounds__(256)
void final_reduce(const float* __restrict__ rowsum, const float* __restrict__ colsum,
                  const float* __restrict__ diag, float* __restrict__ out, int n) {
    const int i = blockIdx.x * 256 + threadIdx.x;
    const int t = threadIdx.x;
    float v = 0.5f * (logf(rowsum[i]) + logf(colsum[i])) - diag[i];
    #pragma unroll
    for (int o = 1; o < 64; o <<= 1) v += __shfl_xor(v, o);
    __shared__ float ws[4];
    if ((t & 63) == 0) ws[t >> 6] = v;
    __syncthreads();
    if (t == 0) atomicAdd(out, (ws[0] + ws[1] + ws[2] + ws[3]) / (float)n);
}

extern "C" void kernel_launch(void* const* d_in, const int* in_sizes, int n_in,
                              void* d_out, int out_size, void* d_ws, size_t ws_size,
                              hipStream_t stream) {
    const float* img = (const float*)d_in[0];
    const float* txt = (const float*)d_in[1];
    float* out = (float*)d_out;

    const int D = 1024;
    const int N = in_sizes[0] / D;   // 8192

    unsigned char* imgq = (unsigned char*)d_ws;
    unsigned char* txtq = imgq + (size_t)N * D;
    float* rowsum = (float*)(txtq + (size_t)N * D);   // rowsum[N] ++ colsum[N]
    float* colsum = rowsum + N;
    float* diag = colsum + N;

    normalize_fp8<<<2 * N / 4, 256, 0, stream>>>(img, txt, (unsigned int*)imgq,
                                                 (unsigned int*)txtq, rowsum, out, N);

    // acc = sum of (16a)(16b) = 256*cos; scale undoes 256 and applies 1/T.
    gemm_exp_kernel<<<(N / BM) * (N / BN), 512, 0, stream>>>(
        imgq, txtq, rowsum, colsum, diag, D, 1.0f / (256.0f * 0.07f));
    final_reduce<<<N / 256, 256, 0, stream>>>(rowsum, colsum, diag, out, N);
}

// Round 9
// 259.669 us; speedup vs baseline: 4.2108x; 3.6737x over previous
//
#include <hip/hip_runtime.h>

// ---------------------------------------------------------------------------
// ContrastiveLoss: loss = mean_i [ 0.5*(LSE_row_i + LSE_col_i) - diag_i ]
// over logits = normalize(img) @ normalize(txt)^T / 0.07, N=8192, D=1024.
// |logit| <= 14.29 -> exp() safe in fp32, no max subtraction needed.
//
// R23 = R14 (verified 184.5us total, gemm 102us, VGPR 84, zero spill)
// + final_reduce FUSED into gemm's last-finishing block; 3rd kernel deleted.
// Pipelined-gemm line CLOSED: R19-R22 all spilled (GB-scale scratch traffic
// at acc=256/128/64) -- the rolling-frag + staging-in-MFMA-window structure
// is compiler-hostile from HIP source; serialized gemm is structure-stable
// at ~100-102us across 128^2 / 256^2 / 128x256 tilings.
// Fusion coherence (per-XCD L2s NOT cross-coherent):
//   - rowsum/colsum: device-scope atomicAdd (coherent) [unchanged]
//   - diag: was plain store (can sit dirty in a remote XCD L2) -> now
//     __hip_atomic_store(AGENT); reducer reads via __hip_atomic_load(AGENT)
//   - each block: __syncthreads (vmcnt drain) + threadfence orders its
//     atomics BEFORE its counter increment; last block (old==grid-1) sees
//     all data at the coherent point. No spin-wait -> no deadlock.
//   - ctr zeroed by normalize_fp8 every graph replay (stream-ordered).
// Carried (R14): barrier-reordered same-buffer prefetch (stage(k+1) after
// reads-done barrier, behind MFMA); R10 producer even/odd chunk interleave
// -> zero-conflict b128 LDS reads (slot = quad ^ ((row>>1)&3)); R13
// inverted XCD swizzle; R4 16B-swizzle b128-only; R1 segment-monotone
// staging.
// ---------------------------------------------------------------------------

#define BM 128
#define BN 128
#define BKB 128   // fp8 K-bytes per iteration (one MFMA k-step)

typedef float floatx4 __attribute__((ext_vector_type(4)));
typedef int   intx4   __attribute__((ext_vector_type(4)));
typedef int   intx8   __attribute__((ext_vector_type(8)));

__device__ __forceinline__ void gload_lds16(const unsigned char* g, unsigned char* lds) {
    __builtin_amdgcn_global_load_lds(
        (const __attribute__((address_space(1))) void*)g,
        (__attribute__((address_space(3))) void*)lds,
        16, 0, 0);
}

// ---- Kernel 1: row L2-normalize, x16, fp32 -> fp8 e4m3, chunk-interleaved --
// One wave per row, 4 rows/block. Rows [0,N)->img, [N,2N)->txt.
// Side duty: zero rowsum/colsum (2N floats), out, and the completion ctr.
__global__ __launch_bounds__(256)
void normalize_fp8(const float* __restrict__ img, const float* __restrict__ txt,
                   unsigned int* __restrict__ oimg, unsigned int* __restrict__ otxt,
                   float* __restrict__ sums, float* __restrict__ out,
                   unsigned int* __restrict__ ctr, int N) {
    const int gi = blockIdx.x * 256 + threadIdx.x;
    if (gi < 2 * N) sums[gi] = 0.f;
    if (gi == 0) { out[0] = 0.f; ctr[0] = 0u; }

    const int gw = blockIdx.x * 4 + (threadIdx.x >> 6);   // row id in [0,2N)
    const int lane = threadIdx.x & 63;
    const float* in = (gw < N) ? img : txt;
    unsigned int* o = (gw < N) ? oimg : otxt;
    const int row = (gw < N) ? gw : gw - N;
    const float4* rp = (const float4*)(in + (size_t)row * 1024);

    float4 v[4];
    float ss = 0.f;
    #pragma unroll
    for (int j = 0; j < 4; ++j) {
        v[j] = rp[j * 64 + lane];
        ss += v[j].x * v[j].x + v[j].y * v[j].y + v[j].z * v[j].z + v[j].w * v[j].w;
    }
    #pragma unroll
    for (int o2 = 1; o2 < 64; o2 <<= 1) ss += __shfl_xor(ss, o2);
    const float inv = 16.0f / fmaxf(sqrtf(ss), 1e-8f);   // x16 quantization scale
    #pragma unroll
    for (int j = 0; j < 4; ++j) {
        int p = __builtin_amdgcn_cvt_pk_fp8_f32(v[j].x * inv, v[j].y * inv, 0, false);
        p = __builtin_amdgcn_cvt_pk_fp8_f32(v[j].z * inv, v[j].w * inv, p, true);
        const int d = j * 64 + lane;
        const int c = (d >> 2) & 7;
        const int pp = (c & 1) * 4 + (c >> 1);
        const int dp = (d & ~31) | (pp * 4 + (d & 3));
        o[(size_t)row * 256 + dp] = (unsigned int)p;
    }
}

// ---- Kernel 2: 128x128-tile NT MX-fp8 GEMM + fused exp/sums/diag/reduce ----
__global__ __launch_bounds__(256)
void gemm_exp_kernel(const unsigned char* __restrict__ A,   // img_q [N][K] fp8 (interleaved)
                     const unsigned char* __restrict__ B,   // txt_q [N][K] fp8 (interleaved)
                     float* __restrict__ rowsum, float* __restrict__ colsum,
                     float* __restrict__ diag, unsigned int* __restrict__ ctr,
                     float* __restrict__ out, int K, float scale, int n) {
    // XCD-inverted swizzle (R13): xcd = id&7 owns bm strip [xcd*8, xcd*8+8).
    const int id = blockIdx.x;
    const int idp = id >> 3;            // position within XCD's sequence
    const int pos = idp & 63;
    const int bm = (id & 7) * 8 + (pos & 7);
    const int bn = (idp >> 6) * 8 + (pos >> 3);

    // LDS: per matrix, 2 windows x [128 rows][64B], slot = chunk ^ ((R>>1)&3).
    __shared__ unsigned char As[2 * BM * 64];   // 16 KB
    __shared__ unsigned char Bs[2 * BN * 64];   // 16 KB

    const int tid = threadIdx.x;
    const int lane = tid & 63;
    const int wave = tid >> 6;
    const int quad = lane >> 4;
    const int lanelo = lane & 15;
    const int wrow = (wave >> 1) * 64;   // wave quadrant within 128x128
    const int wcol = (wave & 1) * 64;

    floatx4 acc[4][4] = {};

    // Staging (R7 pattern): chunk c = wave*128 + lane (and +64); LDS slot =
    // c&3 of row c>>2; global chunk fetched = slot ^ swz(row).
    const int c0 = wave * 128 + lane;
    const int c1 = c0 + 64;
    const int r0 = c0 >> 2, r1 = c1 >> 2;
    const int kg0 = ((c0 & 3) ^ ((r0 >> 1) & 3)) * 16;   // byte in 64B window
    const int kg1 = ((c1 & 3) ^ ((r1 >> 1) & 3)) * 16;

    const unsigned char* pa0 = A + (size_t)bm * BM * K + (size_t)r0 * K + kg0;
    const unsigned char* pa1 = A + (size_t)bm * BM * K + (size_t)r1 * K + kg1;
    const unsigned char* pb0 = B + (size_t)bn * BN * K + (size_t)r0 * K + kg0;
    const unsigned char* pb1 = B + (size_t)bn * BN * K + (size_t)r1 * K + kg1;
    unsigned char* dA0 = As + c0 * 16;
    unsigned char* dA1 = As + c1 * 16;
    unsigned char* dB0 = Bs + c0 * 16;
    unsigned char* dB1 = Bs + c1 * 16;

    // Fragment LDS offsets (R5 geometry): slot = quad ^ swz(R) of one 64B
    // window; read1 = even chunks (k[32q..32q+16)), read2 = +8192 (odd).
    int aoff[4], boff[4];
    #pragma unroll
    for (int t = 0; t < 4; ++t) {
        const int Ra = wrow + t * 16 + lanelo;
        const int Rb = wcol + t * 16 + lanelo;
        aoff[t] = Ra * 64 + ((quad ^ ((Ra >> 1) & 3)) * 16);
        boff[t] = Rb * 64 + ((quad ^ ((Rb >> 1) & 3)) * 16);
    }

    auto stage = [&](int k) {
        #pragma unroll
        for (int w = 0; w < 2; ++w) {
            gload_lds16(pa0 + k + w * 64, dA0 + w * 8192);
            gload_lds16(pa1 + k + w * 64, dA1 + w * 8192);
            gload_lds16(pb0 + k + w * 64, dB0 + w * 8192);
            gload_lds16(pb1 + k + w * 64, dB1 + w * 8192);
        }
    };

    stage(0);
    for (int k = 0; k < K; k += BKB) {
        __syncthreads();                 // staging(k) landed in LDS
        intx8 af[4], bg[4];
        #pragma unroll
        for (int t = 0; t < 4; ++t) {
            const intx4 alo = *(const intx4*)(As + aoff[t]);
            const intx4 ahi = *(const intx4*)(As + 8192 + aoff[t]);
            af[t] = __builtin_shufflevector(alo, ahi, 0, 1, 2, 3, 4, 5, 6, 7);
            const intx4 blo = *(const intx4*)(Bs + boff[t]);
            const intx4 bhi = *(const intx4*)(Bs + 8192 + boff[t]);
            bg[t] = __builtin_shufflevector(blo, bhi, 0, 1, 2, 3, 4, 5, 6, 7);
        }
        __syncthreads();                 // all waves' reads done; LDS free
        if (k + BKB < K) stage(k + BKB); // prefetch next tile behind MFMA

        #pragma unroll
        for (int tm = 0; tm < 4; ++tm)
            #pragma unroll
            for (int tn = 0; tn < 4; ++tn)
                acc[tm][tn] = __builtin_amdgcn_mfma_scale_f32_16x16x128_f8f6f4(
                    af[tm], bg[tn], acc[tm][tn],
                    0, 0,          // cbsz = fp8 e4m3, blgp = fp8 e4m3
                    0, 127,        // A scale: 1.0
                    0, 127);       // B scale: 1.0
    }

    // ---- epilogue: scale, capture diag (device-scope), exp in place ----
    const int growb = bm * BM + wrow;
    const int gcolb = bn * BN + wcol;

    #pragma unroll
    for (int tm = 0; tm < 4; ++tm)
        #pragma unroll
        for (int tn = 0; tn < 4; ++tn)
            #pragma unroll
            for (int r = 0; r < 4; ++r) {
                const float l = acc[tm][tn][r] * scale;
                const int grow = growb + tm * 16 + quad * 4 + r;
                const int gcol = gcolb + tn * 16 + lanelo;
                if (grow == gcol)
                    __hip_atomic_store(&diag[grow], l, __ATOMIC_RELAXED,
                                       __HIP_MEMORY_SCOPE_AGENT);
                acc[tm][tn][r] = __expf(l);
            }

    // ---- row sums: reduce over the 16 lanes sharing a row, then atomicAdd ----
    #pragma unroll
    for (int tm = 0; tm < 4; ++tm) {
        floatx4 rs = acc[tm][0] + acc[tm][1] + acc[tm][2] + acc[tm][3];
        #pragma unroll
        for (int r = 0; r < 4; ++r) {
            float v = rs[r];
            v += __shfl_xor(v, 1);
            v += __shfl_xor(v, 2);
            v += __shfl_xor(v, 4);
            v += __shfl_xor(v, 8);
            if (lanelo == 0)
                atomicAdd(&rowsum[growb + tm * 16 + quad * 4 + r], v);
        }
    }

    // ---- col sums: reduce over quads (xor 16, 32), then atomicAdd ----
    #pragma unroll
    for (int tn = 0; tn < 4; ++tn) {
        float cs = 0.f;
        #pragma unroll
        for (int tm = 0; tm < 4; ++tm)
            cs += acc[tm][tn][0] + acc[tm][tn][1] + acc[tm][tn][2] + acc[tm][tn][3];
        cs += __shfl_xor(cs, 16);
        cs += __shfl_xor(cs, 32);
        if (quad == 0)
            atomicAdd(&colsum[gcolb + tn * 16 + lanelo], cs);
    }

    // ---- fused final reduction: last-finishing block computes the loss ----
    // __syncthreads drains this block's atomic stores (vmcnt(0)) before the
    // counter increment; device-scope counter orders across XCDs. No waiting
    // loop: only the block observing old == grid-1 proceeds.
    __syncthreads();
    __shared__ unsigned int lastFlag;
    if (tid == 0) {
        __threadfence();
        const unsigned int old = atomicAdd(ctr, 1u);
        lastFlag = (old == (unsigned int)(gridDim.x - 1)) ? 1u : 0u;
    }
    __syncthreads();
    if (lastFlag) {
        float a = 0.f;
        for (int i = tid; i < n; i += 256) {
            const float rs = __hip_atomic_load(&rowsum[i], __ATOMIC_RELAXED,
                                               __HIP_MEMORY_SCOPE_AGENT);
            const float cs = __hip_atomic_load(&colsum[i], __ATOMIC_RELAXED,
                                               __HIP_MEMORY_SCOPE_AGENT);
            const float dg = __hip_atomic_load(&diag[i], __ATOMIC_RELAXED,
                                               __HIP_MEMORY_SCOPE_AGENT);
            a += 0.5f * (logf(rs) + logf(cs)) - dg;
        }
        #pragma unroll
        for (int o = 1; o < 64; o <<= 1) a += __shfl_xor(a, o);
        __shared__ float wsr[4];
        if ((tid & 63) == 0) wsr[tid >> 6] = a;
        __syncthreads();
        if (tid == 0) out[0] = (wsr[0] + wsr[1] + wsr[2] + wsr[3]) / (float)n;
    }
}

extern "C" void kernel_launch(void* const* d_in, const int* in_sizes, int n_in,
                              void* d_out, int out_size, void* d_ws, size_t ws_size,
                              hipStream_t stream) {
    const float* img = (const float*)d_in[0];
    const float* txt = (const float*)d_in[1];
    float* out = (float*)d_out;

    const int D = 1024;
    const int N = in_sizes[0] / D;   // 8192

    unsigned char* imgq = (unsigned char*)d_ws;
    unsigned char* txtq = imgq + (size_t)N * D;
    float* rowsum = (float*)(txtq + (size_t)N * D);   // rowsum[N] ++ colsum[N]
    float* colsum = rowsum + N;
    float* diag = colsum + N;
    unsigned int* ctr = (unsigned int*)(diag + N);

    normalize_fp8<<<2 * N / 4, 256, 0, stream>>>(img, txt, (unsigned int*)imgq,
                                                 (unsigned int*)txtq, rowsum, out,
                                                 ctr, N);

    // acc = sum of (16a)(16b) = 256*cos; scale undoes 256 and applies 1/T.
    gemm_exp_kernel<<<(N / BM) * (N / BN), 256, 0, stream>>>(
        imgq, txtq, rowsum, colsum, diag, ctr, out, D, 1.0f / (256.0f * 0.07f), N);
}

// Round 10
// 200.191 us; speedup vs baseline: 5.4619x; 1.2971x over previous
//
#include <hip/hip_runtime.h>

// ---------------------------------------------------------------------------
// ContrastiveLoss: loss = mean_i [ 0.5*(LSE_row_i + LSE_col_i) - diag_i ]
// over logits = normalize(img) @ normalize(txt)^T / 0.07, N=8192, D=1024.
// |logit| <= 14.29 -> exp() safe in fp32, no max subtraction needed.
//
// R24 = R23 MINUS __threadfence() (single-change A/B).
// R23 post-mortem: gemm stretched 102->185us uniformly (MfmaUtil 28->14.6,
// same FETCH). Cause: per-block agent-release fence compiles to
// s_waitcnt + buffer_wbl2 sc1 (full per-XCD L2 writeback) x 4096 blocks.
// The fence is unnecessary: ALL cross-block data (rowsum/colsum atomicAdd,
// diag agent-scope atomic store) are device-scope atomics completing at the
// coherent point (LLC) -- no L2 writeback needed for visibility (m20).
// Ordering data-atomics -> ctr-atomic is given by __syncthreads(): compiler
// emits s_waitcnt vmcnt(0) lgkmcnt(0) before s_barrier (m97 asm), draining
// every wave's atomics before tid0's ctr increment issues.
// Carried (R14 core, verified 102us gemm / 184.5us total, VGPR 84, 0 spill):
// barrier-reordered same-buffer prefetch; R10 producer even/odd chunk
// interleave -> zero-conflict b128 LDS reads (slot = quad ^ ((row>>1)&3));
// R13 inverted XCD swizzle; R4 16B-swizzle b128-only; R1 segment-monotone
// staging. Pipelined-gemm line CLOSED (R19-R22 all spilled).
// ---------------------------------------------------------------------------

#define BM 128
#define BN 128
#define BKB 128   // fp8 K-bytes per iteration (one MFMA k-step)

typedef float floatx4 __attribute__((ext_vector_type(4)));
typedef int   intx4   __attribute__((ext_vector_type(4)));
typedef int   intx8   __attribute__((ext_vector_type(8)));

__device__ __forceinline__ void gload_lds16(const unsigned char* g, unsigned char* lds) {
    __builtin_amdgcn_global_load_lds(
        (const __attribute__((address_space(1))) void*)g,
        (__attribute__((address_space(3))) void*)lds,
        16, 0, 0);
}

// ---- Kernel 1: row L2-normalize, x16, fp32 -> fp8 e4m3, chunk-interleaved --
// One wave per row, 4 rows/block. Rows [0,N)->img, [N,2N)->txt.
// Side duty: zero rowsum/colsum (2N floats), out, and the completion ctr.
__global__ __launch_bounds__(256)
void normalize_fp8(const float* __restrict__ img, const float* __restrict__ txt,
                   unsigned int* __restrict__ oimg, unsigned int* __restrict__ otxt,
                   float* __restrict__ sums, float* __restrict__ out,
                   unsigned int* __restrict__ ctr, int N) {
    const int gi = blockIdx.x * 256 + threadIdx.x;
    if (gi < 2 * N) sums[gi] = 0.f;
    if (gi == 0) { out[0] = 0.f; ctr[0] = 0u; }

    const int gw = blockIdx.x * 4 + (threadIdx.x >> 6);   // row id in [0,2N)
    const int lane = threadIdx.x & 63;
    const float* in = (gw < N) ? img : txt;
    unsigned int* o = (gw < N) ? oimg : otxt;
    const int row = (gw < N) ? gw : gw - N;
    const float4* rp = (const float4*)(in + (size_t)row * 1024);

    float4 v[4];
    float ss = 0.f;
    #pragma unroll
    for (int j = 0; j < 4; ++j) {
        v[j] = rp[j * 64 + lane];
        ss += v[j].x * v[j].x + v[j].y * v[j].y + v[j].z * v[j].z + v[j].w * v[j].w;
    }
    #pragma unroll
    for (int o2 = 1; o2 < 64; o2 <<= 1) ss += __shfl_xor(ss, o2);
    const float inv = 16.0f / fmaxf(sqrtf(ss), 1e-8f);   // x16 quantization scale
    #pragma unroll
    for (int j = 0; j < 4; ++j) {
        int p = __builtin_amdgcn_cvt_pk_fp8_f32(v[j].x * inv, v[j].y * inv, 0, false);
        p = __builtin_amdgcn_cvt_pk_fp8_f32(v[j].z * inv, v[j].w * inv, p, true);
        const int d = j * 64 + lane;
        const int c = (d >> 2) & 7;
        const int pp = (c & 1) * 4 + (c >> 1);
        const int dp = (d & ~31) | (pp * 4 + (d & 3));
        o[(size_t)row * 256 + dp] = (unsigned int)p;
    }
}

// ---- Kernel 2: 128x128-tile NT MX-fp8 GEMM + fused exp/sums/diag/reduce ----
__global__ __launch_bounds__(256)
void gemm_exp_kernel(const unsigned char* __restrict__ A,   // img_q [N][K] fp8 (interleaved)
                     const unsigned char* __restrict__ B,   // txt_q [N][K] fp8 (interleaved)
                     float* __restrict__ rowsum, float* __restrict__ colsum,
                     float* __restrict__ diag, unsigned int* __restrict__ ctr,
                     float* __restrict__ out, int K, float scale, int n) {
    // XCD-inverted swizzle (R13): xcd = id&7 owns bm strip [xcd*8, xcd*8+8).
    const int id = blockIdx.x;
    const int idp = id >> 3;            // position within XCD's sequence
    const int pos = idp & 63;
    const int bm = (id & 7) * 8 + (pos & 7);
    const int bn = (idp >> 6) * 8 + (pos >> 3);

    // LDS: per matrix, 2 windows x [128 rows][64B], slot = chunk ^ ((R>>1)&3).
    __shared__ unsigned char As[2 * BM * 64];   // 16 KB
    __shared__ unsigned char Bs[2 * BN * 64];   // 16 KB

    const int tid = threadIdx.x;
    const int lane = tid & 63;
    const int wave = tid >> 6;
    const int quad = lane >> 4;
    const int lanelo = lane & 15;
    const int wrow = (wave >> 1) * 64;   // wave quadrant within 128x128
    const int wcol = (wave & 1) * 64;

    floatx4 acc[4][4] = {};

    // Staging (R7 pattern): chunk c = wave*128 + lane (and +64); LDS slot =
    // c&3 of row c>>2; global chunk fetched = slot ^ swz(row).
    const int c0 = wave * 128 + lane;
    const int c1 = c0 + 64;
    const int r0 = c0 >> 2, r1 = c1 >> 2;
    const int kg0 = ((c0 & 3) ^ ((r0 >> 1) & 3)) * 16;   // byte in 64B window
    const int kg1 = ((c1 & 3) ^ ((r1 >> 1) & 3)) * 16;

    const unsigned char* pa0 = A + (size_t)bm * BM * K + (size_t)r0 * K + kg0;
    const unsigned char* pa1 = A + (size_t)bm * BM * K + (size_t)r1 * K + kg1;
    const unsigned char* pb0 = B + (size_t)bn * BN * K + (size_t)r0 * K + kg0;
    const unsigned char* pb1 = B + (size_t)bn * BN * K + (size_t)r1 * K + kg1;
    unsigned char* dA0 = As + c0 * 16;
    unsigned char* dA1 = As + c1 * 16;
    unsigned char* dB0 = Bs + c0 * 16;
    unsigned char* dB1 = Bs + c1 * 16;

    // Fragment LDS offsets (R5 geometry): slot = quad ^ swz(R) of one 64B
    // window; read1 = even chunks (k[32q..32q+16)), read2 = +8192 (odd).
    int aoff[4], boff[4];
    #pragma unroll
    for (int t = 0; t < 4; ++t) {
        const int Ra = wrow + t * 16 + lanelo;
        const int Rb = wcol + t * 16 + lanelo;
        aoff[t] = Ra * 64 + ((quad ^ ((Ra >> 1) & 3)) * 16);
        boff[t] = Rb * 64 + ((quad ^ ((Rb >> 1) & 3)) * 16);
    }

    auto stage = [&](int k) {
        #pragma unroll
        for (int w = 0; w < 2; ++w) {
            gload_lds16(pa0 + k + w * 64, dA0 + w * 8192);
            gload_lds16(pa1 + k + w * 64, dA1 + w * 8192);
            gload_lds16(pb0 + k + w * 64, dB0 + w * 8192);
            gload_lds16(pb1 + k + w * 64, dB1 + w * 8192);
        }
    };

    stage(0);
    for (int k = 0; k < K; k += BKB) {
        __syncthreads();                 // staging(k) landed in LDS
        intx8 af[4], bg[4];
        #pragma unroll
        for (int t = 0; t < 4; ++t) {
            const intx4 alo = *(const intx4*)(As + aoff[t]);
            const intx4 ahi = *(const intx4*)(As + 8192 + aoff[t]);
            af[t] = __builtin_shufflevector(alo, ahi, 0, 1, 2, 3, 4, 5, 6, 7);
            const intx4 blo = *(const intx4*)(Bs + boff[t]);
            const intx4 bhi = *(const intx4*)(Bs + 8192 + boff[t]);
            bg[t] = __builtin_shufflevector(blo, bhi, 0, 1, 2, 3, 4, 5, 6, 7);
        }
        __syncthreads();                 // all waves' reads done; LDS free
        if (k + BKB < K) stage(k + BKB); // prefetch next tile behind MFMA

        #pragma unroll
        for (int tm = 0; tm < 4; ++tm)
            #pragma unroll
            for (int tn = 0; tn < 4; ++tn)
                acc[tm][tn] = __builtin_amdgcn_mfma_scale_f32_16x16x128_f8f6f4(
                    af[tm], bg[tn], acc[tm][tn],
                    0, 0,          // cbsz = fp8 e4m3, blgp = fp8 e4m3
                    0, 127,        // A scale: 1.0
                    0, 127);       // B scale: 1.0
    }

    // ---- epilogue: scale, capture diag (device-scope), exp in place ----
    const int growb = bm * BM + wrow;
    const int gcolb = bn * BN + wcol;

    #pragma unroll
    for (int tm = 0; tm < 4; ++tm)
        #pragma unroll
        for (int tn = 0; tn < 4; ++tn)
            #pragma unroll
            for (int r = 0; r < 4; ++r) {
                const float l = acc[tm][tn][r] * scale;
                const int grow = growb + tm * 16 + quad * 4 + r;
                const int gcol = gcolb + tn * 16 + lanelo;
                if (grow == gcol)
                    __hip_atomic_store(&diag[grow], l, __ATOMIC_RELAXED,
                                       __HIP_MEMORY_SCOPE_AGENT);
                acc[tm][tn][r] = __expf(l);
            }

    // ---- row sums: reduce over the 16 lanes sharing a row, then atomicAdd ----
    #pragma unroll
    for (int tm = 0; tm < 4; ++tm) {
        floatx4 rs = acc[tm][0] + acc[tm][1] + acc[tm][2] + acc[tm][3];
        #pragma unroll
        for (int r = 0; r < 4; ++r) {
            float v = rs[r];
            v += __shfl_xor(v, 1);
            v += __shfl_xor(v, 2);
            v += __shfl_xor(v, 4);
            v += __shfl_xor(v, 8);
            if (lanelo == 0)
                atomicAdd(&rowsum[growb + tm * 16 + quad * 4 + r], v);
        }
    }

    // ---- col sums: reduce over quads (xor 16, 32), then atomicAdd ----
    #pragma unroll
    for (int tn = 0; tn < 4; ++tn) {
        float cs = 0.f;
        #pragma unroll
        for (int tm = 0; tm < 4; ++tm)
            cs += acc[tm][tn][0] + acc[tm][tn][1] + acc[tm][tn][2] + acc[tm][tn][3];
        cs += __shfl_xor(cs, 16);
        cs += __shfl_xor(cs, 32);
        if (quad == 0)
            atomicAdd(&colsum[gcolb + tn * 16 + lanelo], cs);
    }

    // ---- fused final reduction: last-finishing block computes the loss ----
    // __syncthreads' implicit s_waitcnt vmcnt(0) drains every wave's data
    // atomics (which complete at the coherent point) BEFORE tid0's ctr
    // increment issues -- no fence needed (all shared data is atomic).
    __syncthreads();
    __shared__ unsigned int lastFlag;
    if (tid == 0) {
        const unsigned int old = atomicAdd(ctr, 1u);
        lastFlag = (old == (unsigned int)(gridDim.x - 1)) ? 1u : 0u;
    }
    __syncthreads();
    if (lastFlag) {
        float a = 0.f;
        for (int i = tid; i < n; i += 256) {
            const float rs = __hip_atomic_load(&rowsum[i], __ATOMIC_RELAXED,
                                               __HIP_MEMORY_SCOPE_AGENT);
            const float cs = __hip_atomic_load(&colsum[i], __ATOMIC_RELAXED,
                                               __HIP_MEMORY_SCOPE_AGENT);
            const float dg = __hip_atomic_load(&diag[i], __ATOMIC_RELAXED,
                                               __HIP_MEMORY_SCOPE_AGENT);
            a += 0.5f * (logf(rs) + logf(cs)) - dg;
        }
        #pragma unroll
        for (int o = 1; o < 64; o <<= 1) a += __shfl_xor(a, o);
        __shared__ float wsr[4];
        if ((tid & 63) == 0) wsr[tid >> 6] = a;
        __syncthreads();
        if (tid == 0) out[0] = (wsr[0] + wsr[1] + wsr[2] + wsr[3]) / (float)n;
    }
}

extern "C" void kernel_launch(void* const* d_in, const int* in_sizes, int n_in,
                              void* d_out, int out_size, void* d_ws, size_t ws_size,
                              hipStream_t stream) {
    const float* img = (const float*)d_in[0];
    const float* txt = (const float*)d_in[1];
    float* out = (float*)d_out;

    const int D = 1024;
    const int N = in_sizes[0] / D;   // 8192

    unsigned char* imgq = (unsigned char*)d_ws;
    unsigned char* txtq = imgq + (size_t)N * D;
    float* rowsum = (float*)(txtq + (size_t)N * D);   // rowsum[N] ++ colsum[N]
    float* colsum = rowsum + N;
    float* diag = colsum + N;
    unsigned int* ctr = (unsigned int*)(diag + N);

    normalize_fp8<<<2 * N / 4, 256, 0, stream>>>(img, txt, (unsigned int*)imgq,
                                                 (unsigned int*)txtq, rowsum, out,
                                                 ctr, N);

    // acc = sum of (16a)(16b) = 256*cos; scale undoes 256 and applies 1/T.
    gemm_exp_kernel<<<(N / BM) * (N / BN), 256, 0, stream>>>(
        imgq, txtq, rowsum, colsum, diag, ctr, out, D, 1.0f / (256.0f * 0.07f), N);
}